// Round 3
// baseline (3937.957 us; speedup 1.0000x reference)
//
#include <hip/hip_runtime.h>

typedef __bf16 bf16;
typedef __attribute__((ext_vector_type(8))) __bf16 bf16x8;
typedef __attribute__((ext_vector_type(4))) __bf16 bf16x4;
typedef __attribute__((ext_vector_type(4))) float f32x4;
typedef __attribute__((ext_vector_type(4))) short s16x4;

#define SCALE 0.17677669529663687f   // 1/sqrt(32)

__device__ __forceinline__ f32x4 mfma16(bf16x8 a, bf16x8 b, f32x4 c) {
  return __builtin_amdgcn_mfma_f32_16x16x32_bf16(a, b, c, 0, 0, 0);
}

// K=16 bf16 MFMA. Layouts (HW-verified rounds 1-2):
//   A: lane holds A[m=l15][k=quad*4+j]   B: lane holds B[k=quad*4+j][n=l15]
//   C: lane holds C[row=quad*4+r][col=l15]
__device__ __forceinline__ f32x4 mfma16k16(bf16x4 a, bf16x4 b, f32x4 c) {
#if __has_builtin(__builtin_amdgcn_mfma_f32_16x16x16bf16_1k)
  return __builtin_amdgcn_mfma_f32_16x16x16bf16_1k(
      __builtin_bit_cast(s16x4, a), __builtin_bit_cast(s16x4, b), c, 0, 0, 0);
#else
  asm("v_mfma_f32_16x16x16_bf16 %0, %1, %2, %0" : "+v"(c) : "v"(a), "v"(b));
  return c;
#endif
}

// ---------------------------------------------------------------------------
// prep: wt[c][k] = bf16(w_qkv[k][c])  (512x1536 -> 1536x512, row-major in k)
//       wpt[c][k] = bf16(w_proj[k][c]) (512x512)
// ---------------------------------------------------------------------------
__global__ void prep_weights(const float* __restrict__ w_qkv,
                             const float* __restrict__ w_proj,
                             bf16* __restrict__ wt, bf16* __restrict__ wpt) {
  __shared__ float tile[32][33];
  int b = blockIdx.x;
  const float* src; bf16* dst; int C, tk, tc;
  if (b < 768) {            // 16 k-tiles x 48 c-tiles
    src = w_qkv; dst = wt; C = 1536; tk = (b & 15) * 32; tc = (b >> 4) * 32;
  } else {                  // 16 x 16 tiles
    b -= 768; src = w_proj; dst = wpt; C = 512; tk = (b & 15) * 32; tc = (b >> 4) * 32;
  }
  int tx = threadIdx.x & 31, ty = threadIdx.x >> 5;
#pragma unroll
  for (int i = 0; i < 4; i++)
    tile[ty + i * 8][tx] = src[(size_t)(tk + ty + i * 8) * C + tc + tx];
  __syncthreads();
#pragma unroll
  for (int i = 0; i < 4; i++)
    dst[(size_t)(tc + ty + i * 8) * 512 + tk + tx] = (bf16)tile[tx][ty + i * 8];
}

// ---------------------------------------------------------------------------
// Fused window attention: one block (8 waves, 512 threads) per window.
// LDS = xs only (66.5 KB) -> TWO blocks per CU: barriers/HBM phases of one
// block hide under compute of the other.
// Wave w handles heads 2w, 2w+1.
// New kv path (associativity): kp = w_k @ (x@Wk + b_k), vp = w_v @ (x@Wv + b_v).
// k/v computed in normal orientation; their C-frags ARE the K=16 A/B frags
// for the tiny linformer projections; kp lands in QK^T A-frag layout, vp in
// PV B-frag layout -> attention fully register-resident.
// ---------------------------------------------------------------------------
__launch_bounds__(512, 4)
__global__ void ewattn(const float* __restrict__ x,
                       const float* __restrict__ b_qkv,
                       const float* __restrict__ w_k,
                       const float* __restrict__ w_v,
                       const float* __restrict__ bias_table,
                       const float* __restrict__ b_proj,
                       const bf16* __restrict__ wt,
                       const bf16* __restrict__ wpt,
                       float* __restrict__ out) {
  __shared__ bf16 xs[64][520];      // phase A/B: bf16(x); phase C/D: reused as ao

  const int tid  = threadIdx.x;
  const int lane = tid & 63;
  const int wid  = tid >> 6;        // wave 0..7 -> heads 2w, 2w+1
  const int l15  = lane & 15;
  const int quad = lane >> 4;
  const int win  = blockIdx.x;
  const float* xw = x + (size_t)win * (64 * 512);

  // ---------------- Phase A: stage x -> LDS (bf16) ----------------
#pragma unroll
  for (int j = 0; j < 8; j++) {
    int i = tid + j * 512;
    int r = i >> 6, c8 = (i & 63) * 8;
    float4 v0 = *reinterpret_cast<const float4*>(xw + r * 512 + c8);
    float4 v1 = *reinterpret_cast<const float4*>(xw + r * 512 + c8 + 4);
    bf16x8 p;
    p[0] = (bf16)v0.x; p[1] = (bf16)v0.y; p[2] = (bf16)v0.z; p[3] = (bf16)v0.w;
    p[4] = (bf16)v1.x; p[5] = (bf16)v1.y; p[6] = (bf16)v1.z; p[7] = (bf16)v1.w;
    *reinterpret_cast<bf16x8*>(&xs[r][c8]) = p;   // row stride 1040 B, 16B aligned
  }
  __syncthreads();

  bf16x4 kpf[2][2], vpf[2][2];      // [hi][nt]: kp in QK^T-A layout, vp in PV-B layout
  bf16x4 qb[2][2][4];               // [hi][ct][tt]: qT frags (B-operand for QK^T)
  bf16x4 ap[2][4];                  // [hi][tt]: softmax probs (A-operand for PV)

  // ---------------- KV pass (per head): k,v full proj then linformer ----------
  for (int hi = 0; hi < 2; hi++) {
    const int h = wid * 2 + hi;
    f32x4 kacc[4][2], vacc[4][2];
#pragma unroll
    for (int tt = 0; tt < 4; tt++)
#pragma unroll
      for (int nt = 0; nt < 2; nt++) {
        kacc[tt][nt] = f32x4{0.f,0.f,0.f,0.f};
        vacc[tt][nt] = f32x4{0.f,0.f,0.f,0.f};
      }
    for (int kt = 0; kt < 16; kt++) {
      bf16x8 af[4];
#pragma unroll
      for (int tt = 0; tt < 4; tt++)
        af[tt] = *(const bf16x8*)&xs[tt * 16 + l15][kt * 32 + quad * 8];
      bf16x8 bwk[2], bwv[2];
#pragma unroll
      for (int nt = 0; nt < 2; nt++) {
        bwk[nt] = *(const bf16x8*)&wt[(size_t)(512  + h * 32 + nt * 16 + l15) * 512 + kt * 32 + quad * 8];
        bwv[nt] = *(const bf16x8*)&wt[(size_t)(1024 + h * 32 + nt * 16 + l15) * 512 + kt * 32 + quad * 8];
      }
#pragma unroll
      for (int tt = 0; tt < 4; tt++)
#pragma unroll
        for (int nt = 0; nt < 2; nt++) {
          kacc[tt][nt] = mfma16(af[tt], bwk[nt], kacc[tt][nt]);
          vacc[tt][nt] = mfma16(af[tt], bwv[nt], vacc[tt][nt]);
        }
    }
    // pack k,v (+proj bias) -> C-frag == K=16 frag (lane=d, reg=token quad*4+r)
    bf16x4 kb[4][2], vb[4][2];
#pragma unroll
    for (int nt = 0; nt < 2; nt++) {
      float bk = b_qkv[512  + h * 32 + nt * 16 + l15];
      float bv = b_qkv[1024 + h * 32 + nt * 16 + l15];
#pragma unroll
      for (int tt = 0; tt < 4; tt++)
#pragma unroll
        for (int r = 0; r < 4; r++) {
          kb[tt][nt][r] = (bf16)(kacc[tt][nt][r] + bk);
          vb[tt][nt][r] = (bf16)(vacc[tt][nt][r] + bv);
        }
    }
    // w_k/w_v fragments: w[p=l15][tok=tt*16+quad*4+j] (float4, L1-hot)
    bf16x4 wkf[4], wvf[4];
#pragma unroll
    for (int tt = 0; tt < 4; tt++) {
      float4 a = *(const float4*)&w_k[l15 * 64 + tt * 16 + quad * 4];
      float4 b = *(const float4*)&w_v[l15 * 64 + tt * 16 + quad * 4];
      wkf[tt][0] = (bf16)a.x; wkf[tt][1] = (bf16)a.y; wkf[tt][2] = (bf16)a.z; wkf[tt][3] = (bf16)a.w;
      wvf[tt][0] = (bf16)b.x; wvf[tt][1] = (bf16)b.y; wvf[tt][2] = (bf16)b.z; wvf[tt][3] = (bf16)b.w;
    }
    // kpT = k^T @ w_k^T (A = kb, B = wkf) -> C lane=p, regs=d  == QK^T A-frag
    // vp  = w_v @ v    (A = wvf, B = vb) -> C lane=d, regs=p  == PV  B-frag
    f32x4 kpacc[2], vpacc[2];
    kpacc[0] = kpacc[1] = vpacc[0] = vpacc[1] = f32x4{0.f,0.f,0.f,0.f};
#pragma unroll
    for (int tt = 0; tt < 4; tt++)
#pragma unroll
      for (int nt = 0; nt < 2; nt++) {
        kpacc[nt] = mfma16k16(kb[tt][nt], wkf[tt], kpacc[nt]);
        vpacc[nt] = mfma16k16(wvf[tt], vb[tt][nt], vpacc[nt]);
      }
#pragma unroll
    for (int nt = 0; nt < 2; nt++)
#pragma unroll
      for (int r = 0; r < 4; r++) {
        kpf[hi][nt][r] = (bf16)kpacc[nt][r];
        vpf[hi][nt][r] = (bf16)vpacc[nt][r];
      }
  }

  // ---------------- Q pass (per head) + attention (register-resident) -------
  for (int hi = 0; hi < 2; hi++) {
    const int h = wid * 2 + hi;
    f32x4 qacc[2][4];
#pragma unroll
    for (int ct = 0; ct < 2; ct++)
#pragma unroll
      for (int tt = 0; tt < 4; tt++) qacc[ct][tt] = f32x4{0.f,0.f,0.f,0.f};
    for (int kt = 0; kt < 16; kt++) {
      bf16x8 aw[2];
#pragma unroll
      for (int ct = 0; ct < 2; ct++)
        aw[ct] = *(const bf16x8*)&wt[(size_t)(h * 32 + ct * 16 + l15) * 512 + kt * 32 + quad * 8];
      bf16x8 bx[4];
#pragma unroll
      for (int tt = 0; tt < 4; tt++)
        bx[tt] = *(const bf16x8*)&xs[tt * 16 + l15][kt * 32 + quad * 8];
#pragma unroll
      for (int ct = 0; ct < 2; ct++)
#pragma unroll
        for (int tt = 0; tt < 4; tt++)
          qacc[ct][tt] = mfma16(aw[ct], bx[tt], qacc[ct][tt]);
    }
#pragma unroll
    for (int ct = 0; ct < 2; ct++)
#pragma unroll
      for (int tt = 0; tt < 4; tt++)
#pragma unroll
        for (int r = 0; r < 4; r++)
          qb[hi][ct][tt][r] = (bf16)((qacc[ct][tt][r] +
                                      b_qkv[h * 32 + ct * 16 + quad * 4 + r]) * SCALE);

    // QK^T (2x K=16) + bias + softmax over p; probs -> PV A-frag
#pragma unroll
    for (int tt = 0; tt < 4; tt++) {
      f32x4 att = mfma16k16(kpf[hi][0], qb[hi][0][tt], f32x4{0.f,0.f,0.f,0.f});
      att = mfma16k16(kpf[hi][1], qb[hi][1][tt], att);
      int n = tt * 16 + l15;
      float e[4], s = 0.f;
#pragma unroll
      for (int r = 0; r < 4; r++) {
        int p = quad * 4 + r;
        int rel = ((n >> 3) - (p >> 3) + 7) * 15 + ((n & 7) - (p & 7) + 7);
        e[r] = __expf(att[r] + bias_table[rel * 16 + h]);
        s += e[r];
      }
      s += __shfl_xor(s, 16); s += __shfl_xor(s, 32);
      float rc = __builtin_amdgcn_rcpf(s);
#pragma unroll
      for (int r = 0; r < 4; r++) ap[hi][tt][r] = (bf16)(e[r] * rc);
    }
  }
  __syncthreads();   // all xs reads done -> reusable as ao

  // ---------------- PV: out_head = probs @ v_proj (K=16 exact) --------------
#pragma unroll
  for (int hi = 0; hi < 2; hi++) {
    const int h = wid * 2 + hi;
#pragma unroll
    for (int tt = 0; tt < 4; tt++)
#pragma unroll
      for (int nd = 0; nd < 2; nd++) {
        f32x4 ov = mfma16k16(ap[hi][tt], vpf[hi][nd], f32x4{0.f,0.f,0.f,0.f});
#pragma unroll
        for (int r = 0; r < 4; r++)
          xs[tt * 16 + quad * 4 + r][h * 32 + nd * 16 + l15] = (bf16)ov[r];
      }
  }
  __syncthreads();   // all heads' ao written

  // ---------------- Phase D: out = ao @ w_proj + b_proj (64 cols/wave) ------
  {
    f32x4 oacc[4][4];
#pragma unroll
    for (int mt = 0; mt < 4; mt++)
#pragma unroll
      for (int nt = 0; nt < 4; nt++) oacc[mt][nt] = f32x4{0.f,0.f,0.f,0.f};
    for (int kt = 0; kt < 16; kt++) {
      bf16x8 af[4];
#pragma unroll
      for (int mt = 0; mt < 4; mt++)
        af[mt] = *(const bf16x8*)&xs[mt * 16 + l15][kt * 32 + quad * 8];
      bf16x8 bw[4];
#pragma unroll
      for (int nt = 0; nt < 4; nt++)
        bw[nt] = *(const bf16x8*)&wpt[(size_t)(wid * 64 + nt * 16 + l15) * 512 + kt * 32 + quad * 8];
#pragma unroll
      for (int mt = 0; mt < 4; mt++)
#pragma unroll
        for (int nt = 0; nt < 4; nt++)
          oacc[mt][nt] = mfma16(af[mt], bw[nt], oacc[mt][nt]);
    }
    float* ow = out + (size_t)win * (64 * 512);
#pragma unroll
    for (int nt = 0; nt < 4; nt++) {
      int c = wid * 64 + nt * 16 + l15;
      float bp = b_proj[c];
#pragma unroll
      for (int mt = 0; mt < 4; mt++)
#pragma unroll
        for (int r = 0; r < 4; r++)
          ow[(size_t)(mt * 16 + quad * 4 + r) * 512 + c] = oacc[mt][nt][r] + bp;
    }
  }
}

extern "C" void kernel_launch(void* const* d_in, const int* in_sizes, int n_in,
                              void* d_out, int out_size, void* d_ws, size_t ws_size,
                              hipStream_t stream) {
  const float* x          = (const float*)d_in[0];
  const float* w_qkv      = (const float*)d_in[1];
  const float* b_qkv      = (const float*)d_in[2];
  const float* w_proj     = (const float*)d_in[3];
  const float* b_proj     = (const float*)d_in[4];
  const float* w_k        = (const float*)d_in[5];
  const float* w_v        = (const float*)d_in[6];
  const float* bias_table = (const float*)d_in[7];
  (void)in_sizes; (void)n_in; (void)out_size; (void)ws_size;

  bf16* wt  = (bf16*)d_ws;            // [1536][512]
  bf16* wpt = wt + 1536 * 512;        // [512][512]

  prep_weights<<<1024, 256, 0, stream>>>(w_qkv, w_proj, wt, wpt);
  ewattn<<<2048, 512, 0, stream>>>(x, b_qkv, w_k, w_v, bias_table, b_proj,
                                   wt, wpt, (float*)d_out);
}

// Round 4
// 3656.269 us; speedup vs baseline: 1.0770x; 1.0770x over previous
//
#include <hip/hip_runtime.h>

typedef __bf16 bf16;
typedef __attribute__((ext_vector_type(8))) __bf16 bf16x8;
typedef __attribute__((ext_vector_type(4))) __bf16 bf16x4;
typedef __attribute__((ext_vector_type(4))) float f32x4;
typedef __attribute__((ext_vector_type(4))) short s16x4;

#define SCALE 0.17677669529663687f   // 1/sqrt(32)

__device__ __forceinline__ f32x4 mfma16(bf16x8 a, bf16x8 b, f32x4 c) {
  return __builtin_amdgcn_mfma_f32_16x16x32_bf16(a, b, c, 0, 0, 0);
}

// K=16 bf16 MFMA. Layouts (HW-verified rounds 1-3):
//   A: lane holds A[m=l15][k=quad*4+j]   B: lane holds B[k=quad*4+j][n=l15]
//   C: lane holds C[row=quad*4+r][col=l15]
__device__ __forceinline__ f32x4 mfma16k16(bf16x4 a, bf16x4 b, f32x4 c) {
#if __has_builtin(__builtin_amdgcn_mfma_f32_16x16x16bf16_1k)
  return __builtin_amdgcn_mfma_f32_16x16x16bf16_1k(
      __builtin_bit_cast(s16x4, a), __builtin_bit_cast(s16x4, b), c, 0, 0, 0);
#else
  asm("v_mfma_f32_16x16x16_bf16 %0, %1, %2, %0" : "+v"(c) : "v"(a), "v"(b));
  return c;
#endif
}

// ---------------------------------------------------------------------------
// prep: wt[c][k] = bf16(w_qkv[k][c])  (512x1536 -> 1536x512, row-major in k)
//       wpt[c][k] = bf16(w_proj[k][c]) (512x512)
// ---------------------------------------------------------------------------
__global__ void prep_weights(const float* __restrict__ w_qkv,
                             const float* __restrict__ w_proj,
                             bf16* __restrict__ wt, bf16* __restrict__ wpt) {
  __shared__ float tile[32][33];
  int b = blockIdx.x;
  const float* src; bf16* dst; int C, tk, tc;
  if (b < 768) {            // 16 k-tiles x 48 c-tiles
    src = w_qkv; dst = wt; C = 1536; tk = (b & 15) * 32; tc = (b >> 4) * 32;
  } else {                  // 16 x 16 tiles
    b -= 768; src = w_proj; dst = wpt; C = 512; tk = (b & 15) * 32; tc = (b >> 4) * 32;
  }
  int tx = threadIdx.x & 31, ty = threadIdx.x >> 5;
#pragma unroll
  for (int i = 0; i < 4; i++)
    tile[ty + i * 8][tx] = src[(size_t)(tk + ty + i * 8) * C + tc + tx];
  __syncthreads();
#pragma unroll
  for (int i = 0; i < 4; i++)
    dst[(size_t)(tc + ty + i * 8) * 512 + tk + tx] = (bf16)tile[tx][ty + i * 8];
}

// ---------------------------------------------------------------------------
// Fused window attention: one block (8 waves, 512 threads) per window.
// LDS = xs only (66.5 KB) -> TWO blocks/CU; barriers/HBM phases of one block
// hide under compute of the other.
// Wave w handles heads 2w, 2w+1 FULLY SEQUENTIALLY (unrolled) so peak live
// registers stay < 128 (4 waves/SIMD cap): kacc+vacc(64) + af(16) +
// bwk/bwv(16) + persistents(~6) + addr ~= 110.  Only vpf[2][2] + ap[2][4]
// (12 VGPRs) survive into the PV / proj phases.
// kv path (associativity): kp = w_k @ (x@Wk + b_k), vp = w_v @ (x@Wv + b_v);
// all attention fragments register-resident (layout chain verified r1-r3).
// ---------------------------------------------------------------------------
__launch_bounds__(512, 4)
__global__ void ewattn(const float* __restrict__ x,
                       const float* __restrict__ b_qkv,
                       const float* __restrict__ w_k,
                       const float* __restrict__ w_v,
                       const float* __restrict__ bias_table,
                       const float* __restrict__ b_proj,
                       const bf16* __restrict__ wt,
                       const bf16* __restrict__ wpt,
                       float* __restrict__ out) {
  __shared__ bf16 xs[64][520];      // phase A/B: bf16(x); phase C/D: reused as ao

  const int tid  = threadIdx.x;
  const int lane = tid & 63;
  const int wid  = tid >> 6;        // wave 0..7 -> heads 2w, 2w+1
  const int l15  = lane & 15;
  const int quad = lane >> 4;
  const int win  = blockIdx.x;
  const float* xw = x + (size_t)win * (64 * 512);

  // ---------------- Phase A: stage x -> LDS (bf16) ----------------
#pragma unroll
  for (int j = 0; j < 8; j++) {
    int i = tid + j * 512;
    int r = i >> 6, c8 = (i & 63) * 8;
    float4 v0 = *reinterpret_cast<const float4*>(xw + r * 512 + c8);
    float4 v1 = *reinterpret_cast<const float4*>(xw + r * 512 + c8 + 4);
    bf16x8 p;
    p[0] = (bf16)v0.x; p[1] = (bf16)v0.y; p[2] = (bf16)v0.z; p[3] = (bf16)v0.w;
    p[4] = (bf16)v1.x; p[5] = (bf16)v1.y; p[6] = (bf16)v1.z; p[7] = (bf16)v1.w;
    *reinterpret_cast<bf16x8*>(&xs[r][c8]) = p;   // row stride 1040 B, 16B aligned
  }
  __syncthreads();

  bf16x4 vpf[2][2];                 // [hi][nd]: vp in PV B-frag layout (persist)
  bf16x4 ap[2][4];                  // [hi][tt]: softmax probs, PV A-frag (persist)

#pragma unroll
  for (int hi = 0; hi < 2; hi++) {
    const int h = wid * 2 + hi;

    // ---- merged KV pass: k,v = x @ Wk/Wv + b (full 64-token, 32-ch) ----
    f32x4 kacc[4][2], vacc[4][2];
#pragma unroll
    for (int tt = 0; tt < 4; tt++)
#pragma unroll
      for (int nt = 0; nt < 2; nt++) {
        kacc[tt][nt] = f32x4{0.f,0.f,0.f,0.f};
        vacc[tt][nt] = f32x4{0.f,0.f,0.f,0.f};
      }
    for (int kt = 0; kt < 16; kt++) {
      bf16x8 af[4];
#pragma unroll
      for (int tt = 0; tt < 4; tt++)
        af[tt] = *(const bf16x8*)&xs[tt * 16 + l15][kt * 32 + quad * 8];
      bf16x8 bwk[2], bwv[2];
#pragma unroll
      for (int nt = 0; nt < 2; nt++) {
        bwk[nt] = *(const bf16x8*)&wt[(size_t)(512  + h * 32 + nt * 16 + l15) * 512 + kt * 32 + quad * 8];
        bwv[nt] = *(const bf16x8*)&wt[(size_t)(1024 + h * 32 + nt * 16 + l15) * 512 + kt * 32 + quad * 8];
      }
#pragma unroll
      for (int tt = 0; tt < 4; tt++)
#pragma unroll
        for (int nt = 0; nt < 2; nt++) {
          kacc[tt][nt] = mfma16(af[tt], bwk[nt], kacc[tt][nt]);
          vacc[tt][nt] = mfma16(af[tt], bwv[nt], vacc[tt][nt]);
        }
    }
    // pack k,v (+proj bias) -> C-frag == K=16 frag (kacc/vacc die here)
    bf16x4 kb[4][2], vb[4][2];
#pragma unroll
    for (int nt = 0; nt < 2; nt++) {
      float bk = b_qkv[512  + h * 32 + nt * 16 + l15];
      float bv = b_qkv[1024 + h * 32 + nt * 16 + l15];
#pragma unroll
      for (int tt = 0; tt < 4; tt++)
#pragma unroll
        for (int r = 0; r < 4; r++) {
          kb[tt][nt][r] = (bf16)(kacc[tt][nt][r] + bk);
          vb[tt][nt][r] = (bf16)(vacc[tt][nt][r] + bv);
        }
    }
    // w_k/w_v fragments: w[p=l15][tok=tt*16+quad*4+j] (float4, L1-hot)
    bf16x4 wkf[4], wvf[4];
#pragma unroll
    for (int tt = 0; tt < 4; tt++) {
      float4 a = *(const float4*)&w_k[l15 * 64 + tt * 16 + quad * 4];
      float4 b = *(const float4*)&w_v[l15 * 64 + tt * 16 + quad * 4];
      wkf[tt][0] = (bf16)a.x; wkf[tt][1] = (bf16)a.y; wkf[tt][2] = (bf16)a.z; wkf[tt][3] = (bf16)a.w;
      wvf[tt][0] = (bf16)b.x; wvf[tt][1] = (bf16)b.y; wvf[tt][2] = (bf16)b.z; wvf[tt][3] = (bf16)b.w;
    }
    // kpT = k^T @ w_k^T -> C lane=p, regs=d  == QK^T A-frag
    // vp  = w_v @ v     -> C lane=d, regs=p  == PV  B-frag
    f32x4 kpacc[2], vpacc[2];
    kpacc[0] = kpacc[1] = vpacc[0] = vpacc[1] = f32x4{0.f,0.f,0.f,0.f};
#pragma unroll
    for (int tt = 0; tt < 4; tt++)
#pragma unroll
      for (int nt = 0; nt < 2; nt++) {
        kpacc[nt] = mfma16k16(kb[tt][nt], wkf[tt], kpacc[nt]);
        vpacc[nt] = mfma16k16(wvf[tt], vb[tt][nt], vpacc[nt]);
      }
    bf16x4 kpf[2];
#pragma unroll
    for (int nt = 0; nt < 2; nt++)
#pragma unroll
      for (int r = 0; r < 4; r++) {
        kpf[nt][r]      = (bf16)kpacc[nt][r];
        vpf[hi][nt][r]  = (bf16)vpacc[nt][r];
      }

    // ---- Q pass (kb/vb/wkf/wvf dead; only kpf + prior persistents live) ----
    f32x4 qacc[2][4];
#pragma unroll
    for (int ct = 0; ct < 2; ct++)
#pragma unroll
      for (int tt = 0; tt < 4; tt++) qacc[ct][tt] = f32x4{0.f,0.f,0.f,0.f};
    for (int kt = 0; kt < 16; kt++) {
      bf16x8 aw[2];
#pragma unroll
      for (int ct = 0; ct < 2; ct++)
        aw[ct] = *(const bf16x8*)&wt[(size_t)(h * 32 + ct * 16 + l15) * 512 + kt * 32 + quad * 8];
      bf16x8 bx[4];
#pragma unroll
      for (int tt = 0; tt < 4; tt++)
        bx[tt] = *(const bf16x8*)&xs[tt * 16 + l15][kt * 32 + quad * 8];
#pragma unroll
      for (int ct = 0; ct < 2; ct++)
#pragma unroll
        for (int tt = 0; tt < 4; tt++)
          qacc[ct][tt] = mfma16(aw[ct], bx[tt], qacc[ct][tt]);
    }
    bf16x4 qb[2][4];
#pragma unroll
    for (int ct = 0; ct < 2; ct++)
#pragma unroll
      for (int tt = 0; tt < 4; tt++)
#pragma unroll
        for (int r = 0; r < 4; r++)
          qb[ct][tt][r] = (bf16)((qacc[ct][tt][r] +
                                  b_qkv[h * 32 + ct * 16 + quad * 4 + r]) * SCALE);

    // ---- QK^T (2x K=16) + bias + softmax over p -> ap (PV A-frag) ----
#pragma unroll
    for (int tt = 0; tt < 4; tt++) {
      f32x4 att = mfma16k16(kpf[0], qb[0][tt], f32x4{0.f,0.f,0.f,0.f});
      att = mfma16k16(kpf[1], qb[1][tt], att);
      int n = tt * 16 + l15;
      float e[4], s = 0.f;
#pragma unroll
      for (int r = 0; r < 4; r++) {
        int p = quad * 4 + r;
        int rel = ((n >> 3) - (p >> 3) + 7) * 15 + ((n & 7) - (p & 7) + 7);
        e[r] = __expf(att[r] + bias_table[rel * 16 + h]);
        s += e[r];
      }
      s += __shfl_xor(s, 16); s += __shfl_xor(s, 32);
      float rc = __builtin_amdgcn_rcpf(s);
#pragma unroll
      for (int r = 0; r < 4; r++) ap[hi][tt][r] = (bf16)(e[r] * rc);
    }
  }
  __syncthreads();   // all xs reads done -> reusable as ao

  // ---------------- PV: out_head = probs @ v_proj (K=16 exact) --------------
#pragma unroll
  for (int hi = 0; hi < 2; hi++) {
    const int h = wid * 2 + hi;
#pragma unroll
    for (int tt = 0; tt < 4; tt++)
#pragma unroll
      for (int nd = 0; nd < 2; nd++) {
        f32x4 ov = mfma16k16(ap[hi][tt], vpf[hi][nd], f32x4{0.f,0.f,0.f,0.f});
#pragma unroll
        for (int r = 0; r < 4; r++)
          xs[tt * 16 + quad * 4 + r][h * 32 + nd * 16 + l15] = (bf16)ov[r];
      }
  }
  __syncthreads();   // all heads' ao written

  // ---------------- Phase D: out = ao @ w_proj + b_proj (64 cols/wave) ------
  {
    f32x4 oacc[4][4];
#pragma unroll
    for (int mt = 0; mt < 4; mt++)
#pragma unroll
      for (int nt = 0; nt < 4; nt++) oacc[mt][nt] = f32x4{0.f,0.f,0.f,0.f};
    for (int kt = 0; kt < 16; kt++) {
      bf16x8 af[4];
#pragma unroll
      for (int mt = 0; mt < 4; mt++)
        af[mt] = *(const bf16x8*)&xs[mt * 16 + l15][kt * 32 + quad * 8];
      bf16x8 bw[4];
#pragma unroll
      for (int nt = 0; nt < 4; nt++)
        bw[nt] = *(const bf16x8*)&wpt[(size_t)(wid * 64 + nt * 16 + l15) * 512 + kt * 32 + quad * 8];
#pragma unroll
      for (int mt = 0; mt < 4; mt++)
#pragma unroll
        for (int nt = 0; nt < 4; nt++)
          oacc[mt][nt] = mfma16(af[mt], bw[nt], oacc[mt][nt]);
    }
    float* ow = out + (size_t)win * (64 * 512);
#pragma unroll
    for (int nt = 0; nt < 4; nt++) {
      int c = wid * 64 + nt * 16 + l15;
      float bp = b_proj[c];
#pragma unroll
      for (int mt = 0; mt < 4; mt++)
#pragma unroll
        for (int r = 0; r < 4; r++)
          ow[(size_t)(mt * 16 + quad * 4 + r) * 512 + c] = oacc[mt][nt][r] + bp;
    }
  }
}

extern "C" void kernel_launch(void* const* d_in, const int* in_sizes, int n_in,
                              void* d_out, int out_size, void* d_ws, size_t ws_size,
                              hipStream_t stream) {
  const float* x          = (const float*)d_in[0];
  const float* w_qkv      = (const float*)d_in[1];
  const float* b_qkv      = (const float*)d_in[2];
  const float* w_proj     = (const float*)d_in[3];
  const float* b_proj     = (const float*)d_in[4];
  const float* w_k        = (const float*)d_in[5];
  const float* w_v        = (const float*)d_in[6];
  const float* bias_table = (const float*)d_in[7];
  (void)in_sizes; (void)n_in; (void)out_size; (void)ws_size;

  bf16* wt  = (bf16*)d_ws;            // [1536][512]
  bf16* wpt = wt + 1536 * 512;        // [512][512]

  prep_weights<<<1024, 256, 0, stream>>>(w_qkv, w_proj, wt, wpt);
  ewattn<<<2048, 512, 0, stream>>>(x, b_qkv, w_k, w_v, bias_table, b_proj,
                                   wt, wpt, (float*)d_out);
}

// Round 5
// 970.170 us; speedup vs baseline: 4.0590x; 3.7687x over previous
//
#include <hip/hip_runtime.h>

typedef __bf16 bf16;
typedef __attribute__((ext_vector_type(8))) __bf16 bf16x8;
typedef __attribute__((ext_vector_type(4))) __bf16 bf16x4;
typedef __attribute__((ext_vector_type(4))) float f32x4;
typedef __attribute__((ext_vector_type(4))) short s16x4;

#define SCALE 0.17677669529663687f   // 1/sqrt(32)

// full compiler fence: stops cross-phase load hoisting / CSE that exploded
// live ranges in rounds 3-4 (scratch spill -> 13 GB HBM traffic)
#define PHASE_FENCE() asm volatile("" ::: "memory")

__device__ __forceinline__ f32x4 mfma16(bf16x8 a, bf16x8 b, f32x4 c) {
  return __builtin_amdgcn_mfma_f32_16x16x32_bf16(a, b, c, 0, 0, 0);
}

// K=16 bf16 MFMA. Layouts (HW-verified rounds 1-4):
//   A: lane holds A[m=l15][k=quad*4+j]   B: lane holds B[k=quad*4+j][n=l15]
//   C: lane holds C[row=quad*4+r][col=l15]
__device__ __forceinline__ f32x4 mfma16k16(bf16x4 a, bf16x4 b, f32x4 c) {
#if __has_builtin(__builtin_amdgcn_mfma_f32_16x16x16bf16_1k)
  return __builtin_amdgcn_mfma_f32_16x16x16bf16_1k(
      __builtin_bit_cast(s16x4, a), __builtin_bit_cast(s16x4, b), c, 0, 0, 0);
#else
  asm("v_mfma_f32_16x16x16_bf16 %0, %1, %2, %0" : "+v"(c) : "v"(a), "v"(b));
  return c;
#endif
}

// ---------------------------------------------------------------------------
// prep: wt[c][k] = bf16(w_qkv[k][c])  (512x1536 -> 1536x512, row-major in k)
//       wpt[c][k] = bf16(w_proj[k][c]) (512x512)
// ---------------------------------------------------------------------------
__global__ void prep_weights(const float* __restrict__ w_qkv,
                             const float* __restrict__ w_proj,
                             bf16* __restrict__ wt, bf16* __restrict__ wpt) {
  __shared__ float tile[32][33];
  int b = blockIdx.x;
  const float* src; bf16* dst; int C, tk, tc;
  if (b < 768) {            // 16 k-tiles x 48 c-tiles
    src = w_qkv; dst = wt; C = 1536; tk = (b & 15) * 32; tc = (b >> 4) * 32;
  } else {                  // 16 x 16 tiles
    b -= 768; src = w_proj; dst = wpt; C = 512; tk = (b & 15) * 32; tc = (b >> 4) * 32;
  }
  int tx = threadIdx.x & 31, ty = threadIdx.x >> 5;
#pragma unroll
  for (int i = 0; i < 4; i++)
    tile[ty + i * 8][tx] = src[(size_t)(tk + ty + i * 8) * C + tc + tx];
  __syncthreads();
#pragma unroll
  for (int i = 0; i < 4; i++)
    dst[(size_t)(tc + ty + i * 8) * 512 + tk + tx] = (bf16)tile[tx][ty + i * 8];
}

// ---------------------------------------------------------------------------
// Fused window attention: one block (8 waves, 512 threads) per window.
// LDS = xs only (66.5 KB) -> TWO blocks/CU.
// Wave w handles heads 2w, 2w+1 sequentially (unrolled, static indexing).
// Register budget (128 cap from launch_bounds(512,4)) held by SPLITTING the
// K and V passes (peak live ~98) and fencing each phase boundary so the
// scheduler cannot widen live ranges across phases (r3/r4 spill lesson).
// kv path (associativity): kp = w_k @ (x@Wk + b_k), vp = w_v @ (x@Wv + b_v);
// attention fully register-resident (fragment-layout chain verified r1-r4).
// ---------------------------------------------------------------------------
__launch_bounds__(512, 4)
__global__ void ewattn(const float* __restrict__ x,
                       const float* __restrict__ b_qkv,
                       const float* __restrict__ w_k,
                       const float* __restrict__ w_v,
                       const float* __restrict__ bias_table,
                       const float* __restrict__ b_proj,
                       const bf16* __restrict__ wt,
                       const bf16* __restrict__ wpt,
                       float* __restrict__ out) {
  __shared__ bf16 xs[64][520];      // phase A/B: bf16(x); phase C/D: reused as ao

  const int tid  = threadIdx.x;
  const int lane = tid & 63;
  const int wid  = tid >> 6;        // wave 0..7 -> heads 2w, 2w+1
  const int l15  = lane & 15;
  const int quad = lane >> 4;
  const int win  = blockIdx.x;
  const float* xw = x + (size_t)win * (64 * 512);

  // ---------------- Phase A: stage x -> LDS (bf16) ----------------
#pragma unroll
  for (int j = 0; j < 8; j++) {
    int i = tid + j * 512;
    int r = i >> 6, c8 = (i & 63) * 8;
    float4 v0 = *reinterpret_cast<const float4*>(xw + r * 512 + c8);
    float4 v1 = *reinterpret_cast<const float4*>(xw + r * 512 + c8 + 4);
    bf16x8 p;
    p[0] = (bf16)v0.x; p[1] = (bf16)v0.y; p[2] = (bf16)v0.z; p[3] = (bf16)v0.w;
    p[4] = (bf16)v1.x; p[5] = (bf16)v1.y; p[6] = (bf16)v1.z; p[7] = (bf16)v1.w;
    *reinterpret_cast<bf16x8*>(&xs[r][c8]) = p;   // row stride 1040 B, 16B aligned
  }
  __syncthreads();

  bf16x4 vpf[2][2];                 // [hi][nd]: vp in PV B-frag layout (persist)
  bf16x4 ap[2][4];                  // [hi][tt]: softmax probs, PV A-frag (persist)

#pragma unroll
  for (int hi = 0; hi < 2; hi++) {
    const int h = wid * 2 + hi;

    // ---- K pass: k = x @ Wk + b_k  (acc 32 + af 16 + bw 8 live) ----
    bf16x4 kb[4][2];
    {
      f32x4 kacc[4][2];
#pragma unroll
      for (int tt = 0; tt < 4; tt++)
#pragma unroll
        for (int nt = 0; nt < 2; nt++) kacc[tt][nt] = f32x4{0.f,0.f,0.f,0.f};
      for (int kt = 0; kt < 16; kt++) {
        bf16x8 af[4];
#pragma unroll
        for (int tt = 0; tt < 4; tt++)
          af[tt] = *(const bf16x8*)&xs[tt * 16 + l15][kt * 32 + quad * 8];
        bf16x8 bwk[2];
#pragma unroll
        for (int nt = 0; nt < 2; nt++)
          bwk[nt] = *(const bf16x8*)&wt[(size_t)(512 + h * 32 + nt * 16 + l15) * 512 + kt * 32 + quad * 8];
#pragma unroll
        for (int tt = 0; tt < 4; tt++)
#pragma unroll
          for (int nt = 0; nt < 2; nt++)
            kacc[tt][nt] = mfma16(af[tt], bwk[nt], kacc[tt][nt]);
      }
#pragma unroll
      for (int nt = 0; nt < 2; nt++) {
        float bk = b_qkv[512 + h * 32 + nt * 16 + l15];
#pragma unroll
        for (int tt = 0; tt < 4; tt++)
#pragma unroll
          for (int r = 0; r < 4; r++)
            kb[tt][nt][r] = (bf16)(kacc[tt][nt][r] + bk);
      }
    }
    PHASE_FENCE();

    // ---- V pass: v = x @ Wv + b_v ----
    bf16x4 vb[4][2];
    {
      f32x4 vacc[4][2];
#pragma unroll
      for (int tt = 0; tt < 4; tt++)
#pragma unroll
        for (int nt = 0; nt < 2; nt++) vacc[tt][nt] = f32x4{0.f,0.f,0.f,0.f};
      for (int kt = 0; kt < 16; kt++) {
        bf16x8 af[4];
#pragma unroll
        for (int tt = 0; tt < 4; tt++)
          af[tt] = *(const bf16x8*)&xs[tt * 16 + l15][kt * 32 + quad * 8];
        bf16x8 bwv[2];
#pragma unroll
        for (int nt = 0; nt < 2; nt++)
          bwv[nt] = *(const bf16x8*)&wt[(size_t)(1024 + h * 32 + nt * 16 + l15) * 512 + kt * 32 + quad * 8];
#pragma unroll
        for (int tt = 0; tt < 4; tt++)
#pragma unroll
          for (int nt = 0; nt < 2; nt++)
            vacc[tt][nt] = mfma16(af[tt], bwv[nt], vacc[tt][nt]);
      }
#pragma unroll
      for (int nt = 0; nt < 2; nt++) {
        float bv = b_qkv[1024 + h * 32 + nt * 16 + l15];
#pragma unroll
        for (int tt = 0; tt < 4; tt++)
#pragma unroll
          for (int r = 0; r < 4; r++)
            vb[tt][nt][r] = (bf16)(vacc[tt][nt][r] + bv);
      }
    }
    PHASE_FENCE();

    // ---- linformer proj: kpT = k^T @ w_k^T, vp = w_v @ v (K=16) ----
    bf16x4 kpf[2];
    {
      bf16x4 wkf[4], wvf[4];        // w[p=l15][tok=tt*16+quad*4+j], L1-hot
#pragma unroll
      for (int tt = 0; tt < 4; tt++) {
        float4 a = *(const float4*)&w_k[l15 * 64 + tt * 16 + quad * 4];
        float4 b = *(const float4*)&w_v[l15 * 64 + tt * 16 + quad * 4];
        wkf[tt][0] = (bf16)a.x; wkf[tt][1] = (bf16)a.y; wkf[tt][2] = (bf16)a.z; wkf[tt][3] = (bf16)a.w;
        wvf[tt][0] = (bf16)b.x; wvf[tt][1] = (bf16)b.y; wvf[tt][2] = (bf16)b.z; wvf[tt][3] = (bf16)b.w;
      }
      f32x4 kpacc[2], vpacc[2];
      kpacc[0] = kpacc[1] = vpacc[0] = vpacc[1] = f32x4{0.f,0.f,0.f,0.f};
#pragma unroll
      for (int tt = 0; tt < 4; tt++)
#pragma unroll
        for (int nt = 0; nt < 2; nt++) {
          kpacc[nt] = mfma16k16(kb[tt][nt], wkf[tt], kpacc[nt]);   // C lane=p, regs=d
          vpacc[nt] = mfma16k16(wvf[tt], vb[tt][nt], vpacc[nt]);   // C lane=d, regs=p
        }
#pragma unroll
      for (int nt = 0; nt < 2; nt++)
#pragma unroll
        for (int r = 0; r < 4; r++) {
          kpf[nt][r]     = (bf16)kpacc[nt][r];
          vpf[hi][nt][r] = (bf16)vpacc[nt][r];
        }
    }
    PHASE_FENCE();

    // ---- Q pass: qT = Wq^T @ x^T (C: lane=token, regs=channel) ----
    bf16x4 qb[2][4];
    {
      f32x4 qacc[2][4];
#pragma unroll
      for (int ct = 0; ct < 2; ct++)
#pragma unroll
        for (int tt = 0; tt < 4; tt++) qacc[ct][tt] = f32x4{0.f,0.f,0.f,0.f};
      for (int kt = 0; kt < 16; kt++) {
        bf16x8 aw[2];
#pragma unroll
        for (int ct = 0; ct < 2; ct++)
          aw[ct] = *(const bf16x8*)&wt[(size_t)(h * 32 + ct * 16 + l15) * 512 + kt * 32 + quad * 8];
        bf16x8 bx[4];
#pragma unroll
        for (int tt = 0; tt < 4; tt++)
          bx[tt] = *(const bf16x8*)&xs[tt * 16 + l15][kt * 32 + quad * 8];
#pragma unroll
        for (int ct = 0; ct < 2; ct++)
#pragma unroll
          for (int tt = 0; tt < 4; tt++)
            qacc[ct][tt] = mfma16(aw[ct], bx[tt], qacc[ct][tt]);
      }
#pragma unroll
      for (int ct = 0; ct < 2; ct++)
#pragma unroll
        for (int tt = 0; tt < 4; tt++)
#pragma unroll
          for (int r = 0; r < 4; r++)
            qb[ct][tt][r] = (bf16)((qacc[ct][tt][r] +
                                    b_qkv[h * 32 + ct * 16 + quad * 4 + r]) * SCALE);
    }
    PHASE_FENCE();

    // ---- QK^T (2x K=16) + bias + softmax over p -> ap (PV A-frag) ----
#pragma unroll
    for (int tt = 0; tt < 4; tt++) {
      f32x4 att = mfma16k16(kpf[0], qb[0][tt], f32x4{0.f,0.f,0.f,0.f});
      att = mfma16k16(kpf[1], qb[1][tt], att);
      int n = tt * 16 + l15;
      float e[4], s = 0.f;
#pragma unroll
      for (int r = 0; r < 4; r++) {
        int p = quad * 4 + r;
        int rel = ((n >> 3) - (p >> 3) + 7) * 15 + ((n & 7) - (p & 7) + 7);
        e[r] = __expf(att[r] + bias_table[rel * 16 + h]);
        s += e[r];
      }
      s += __shfl_xor(s, 16); s += __shfl_xor(s, 32);
      float rc = __builtin_amdgcn_rcpf(s);
#pragma unroll
      for (int r = 0; r < 4; r++) ap[hi][tt][r] = (bf16)(e[r] * rc);
    }
    PHASE_FENCE();
  }
  __syncthreads();   // all xs reads done -> reusable as ao

  // ---------------- PV: out_head = probs @ v_proj (K=16 exact) --------------
#pragma unroll
  for (int hi = 0; hi < 2; hi++) {
    const int h = wid * 2 + hi;
#pragma unroll
    for (int tt = 0; tt < 4; tt++)
#pragma unroll
      for (int nd = 0; nd < 2; nd++) {
        f32x4 ov = mfma16k16(ap[hi][tt], vpf[hi][nd], f32x4{0.f,0.f,0.f,0.f});
#pragma unroll
        for (int r = 0; r < 4; r++)
          xs[tt * 16 + quad * 4 + r][h * 32 + nd * 16 + l15] = (bf16)ov[r];
      }
  }
  __syncthreads();   // all heads' ao written

  // ---------------- Phase D: out = ao @ w_proj + b_proj (64 cols/wave) ------
  {
    f32x4 oacc[4][4];
#pragma unroll
    for (int mt = 0; mt < 4; mt++)
#pragma unroll
      for (int nt = 0; nt < 4; nt++) oacc[mt][nt] = f32x4{0.f,0.f,0.f,0.f};
    for (int kt = 0; kt < 16; kt++) {
      bf16x8 af[4];
#pragma unroll
      for (int mt = 0; mt < 4; mt++)
        af[mt] = *(const bf16x8*)&xs[mt * 16 + l15][kt * 32 + quad * 8];
      bf16x8 bw[4];
#pragma unroll
      for (int nt = 0; nt < 4; nt++)
        bw[nt] = *(const bf16x8*)&wpt[(size_t)(wid * 64 + nt * 16 + l15) * 512 + kt * 32 + quad * 8];
#pragma unroll
      for (int mt = 0; mt < 4; mt++)
#pragma unroll
        for (int nt = 0; nt < 4; nt++)
          oacc[mt][nt] = mfma16(af[mt], bw[nt], oacc[mt][nt]);
    }
    float* ow = out + (size_t)win * (64 * 512);
#pragma unroll
    for (int nt = 0; nt < 4; nt++) {
      int c = wid * 64 + nt * 16 + l15;
      float bp = b_proj[c];
#pragma unroll
      for (int mt = 0; mt < 4; mt++)
#pragma unroll
        for (int r = 0; r < 4; r++)
          ow[(size_t)(mt * 16 + quad * 4 + r) * 512 + c] = oacc[mt][nt][r] + bp;
    }
  }
}

extern "C" void kernel_launch(void* const* d_in, const int* in_sizes, int n_in,
                              void* d_out, int out_size, void* d_ws, size_t ws_size,
                              hipStream_t stream) {
  const float* x          = (const float*)d_in[0];
  const float* w_qkv      = (const float*)d_in[1];
  const float* b_qkv      = (const float*)d_in[2];
  const float* w_proj     = (const float*)d_in[3];
  const float* b_proj     = (const float*)d_in[4];
  const float* w_k        = (const float*)d_in[5];
  const float* w_v        = (const float*)d_in[6];
  const float* bias_table = (const float*)d_in[7];
  (void)in_sizes; (void)n_in; (void)out_size; (void)ws_size;

  bf16* wt  = (bf16*)d_ws;            // [1536][512]
  bf16* wpt = wt + 1536 * 512;        // [512][512]

  prep_weights<<<1024, 256, 0, stream>>>(w_qkv, w_proj, wt, wpt);
  ewattn<<<2048, 512, 0, stream>>>(x, b_qkv, w_k, w_v, bias_table, b_proj,
                                   wt, wpt, (float*)d_out);
}